// Round 2
// baseline (429.092 us; speedup 1.0000x reference)
//
#include <hip/hip_runtime.h>
#include <math.h>

#define TPB 512

// ---- LDS layout (float offsets), with lifetime-based overlays ----
// OX   : x image, alive whole kernel (dyn conv re-reads it)
// OW1/OC1/OW2 : contiguous 3360-float region; dead after conv5 -> reused for conv2 partials (3240)
// OW3  : conv2 weights, dead after conv2-main
// OY   : 1690 floats: conv5 partials(1440) -> dyn y(1690) -> c3(1620) -> fc320 partials(400)
#define OX    0
#define OW1   784      // 392
#define OC1   1176     // 968  (conv7 pooled out [8,11,11])
#define OW2   2144     // 2000
#define OW3   4144     // 5000
#define OY    9144     // 1690
#define OF    10834    // 90
#define OH    10924    // 32
#define OK    10956    // 40
#define OP3   10996    // 320
#define OA1   11316    // 50
#define OZ    11366    // 10
#define SM_TOT 11376   // 45.5 KB -> 3 blocks/CU if VGPR <= ~85

__global__ __launch_bounds__(TPB) void fused_forward(
    const float* __restrict__ x,
    const float* __restrict__ kf_w1, const float* __restrict__ kf_b1,
    const float* __restrict__ kf_w2, const float* __restrict__ kf_b2,
    const float* __restrict__ kf_fc1_w, const float* __restrict__ kf_fc1_b,
    const float* __restrict__ kf_fc2_w, const float* __restrict__ kf_fc2_b,
    const float* __restrict__ conv2_w, const float* __restrict__ conv2_b,
    const float* __restrict__ fc1_w, const float* __restrict__ fc1_b,
    const float* __restrict__ fc2_w, const float* __restrict__ fc2_b,
    float* __restrict__ out)
{
    __shared__ float sm[SM_TOT];
    const int tid = threadIdx.x;
    const int n = blockIdx.x;

    // ---- stage 0: vectorized loads (all region offsets are 16B-aligned) ----
    {
        const float4* xg = (const float4*)(x + (long long)n * 784);
        float4* d = (float4*)&sm[OX];
        for (int i = tid; i < 196; i += TPB) d[i] = xg[i];
        float4* d1 = (float4*)&sm[OW1];
        for (int i = tid; i < 98; i += TPB) d1[i] = ((const float4*)kf_w1)[i];
        float4* d2 = (float4*)&sm[OW2];
        for (int i = tid; i < 500; i += TPB) d2[i] = ((const float4*)kf_w2)[i];
        float4* d3 = (float4*)&sm[OW3];
        for (int i = tid; i < 1250; i += TPB) d3[i] = ((const float4*)conv2_w)[i];
    }
    __syncthreads();

    // ---- conv7 (28->22) + pool (->11) + relu : 968 outputs, 2 passes ----
    for (int idx = tid; idx < 968; idx += TPB) {
        int oc = idx / 121, rem = idx % 121;
        int py = rem / 11, px = rem % 11;
        float a00 = 0.f, a01 = 0.f, a10 = 0.f, a11 = 0.f;
        const float* w = &sm[OW1 + oc * 49];
        #pragma unroll
        for (int ky = 0; ky < 7; ++ky) {
            const float* x0 = &sm[OX + (2 * py + ky) * 28 + 2 * px];
            const float* x1 = x0 + 28;
            float r0[8], r1[8];
            #pragma unroll
            for (int t = 0; t < 8; ++t) { r0[t] = x0[t]; r1[t] = x1[t]; }
            #pragma unroll
            for (int kx = 0; kx < 7; ++kx) {
                float wv = w[ky * 7 + kx];
                a00 = fmaf(wv, r0[kx],     a00);
                a01 = fmaf(wv, r0[kx + 1], a01);
                a10 = fmaf(wv, r1[kx],     a10);
                a11 = fmaf(wv, r1[kx + 1], a11);
            }
        }
        float m = fmaxf(fmaxf(a00, a01), fmaxf(a10, a11)) + kf_b1[oc];
        sm[OC1 + idx] = fmaxf(m, 0.f);
    }
    __syncthreads();

    // ---- conv5 (11->7) + pool (->3) + relu, split 4-way over ic ----
    if (tid < 360) {
        int g = tid / 90, o = tid % 90;          // g = ic-group (2 ic each)
        int oc = o / 9, rem = o % 9, py = rem / 3, px = rem % 3;
        float a00 = 0.f, a01 = 0.f, a10 = 0.f, a11 = 0.f;
        #pragma unroll
        for (int icg = 0; icg < 2; ++icg) {
            int ic = g * 2 + icg;
            const float* wb = &sm[OW2 + (oc * 8 + ic) * 25];
            #pragma unroll
            for (int ky = 0; ky < 5; ++ky) {
                const float* x0 = &sm[OC1 + ic * 121 + (2 * py + ky) * 11 + 2 * px];
                const float* x1 = x0 + 11;
                float r0[6], r1[6];
                #pragma unroll
                for (int t = 0; t < 6; ++t) { r0[t] = x0[t]; r1[t] = x1[t]; }
                #pragma unroll
                for (int kx = 0; kx < 5; ++kx) {
                    float wv = wb[ky * 5 + kx];
                    a00 = fmaf(wv, r0[kx],     a00);
                    a01 = fmaf(wv, r0[kx + 1], a01);
                    a10 = fmaf(wv, r1[kx],     a10);
                    a11 = fmaf(wv, r1[kx + 1], a11);
                }
            }
        }
        sm[OY + 0 * 360 + tid] = a00;
        sm[OY + 1 * 360 + tid] = a01;
        sm[OY + 2 * 360 + tid] = a10;
        sm[OY + 3 * 360 + tid] = a11;
    }
    __syncthreads();
    if (tid < 90) {
        int oc = tid / 9;
        float a[4];
        #pragma unroll
        for (int q = 0; q < 4; ++q)
            a[q] = sm[OY + q * 360 + tid] + sm[OY + q * 360 + 90 + tid]
                 + sm[OY + q * 360 + 180 + tid] + sm[OY + q * 360 + 270 + tid];
        float m = fmaxf(fmaxf(a[0], a[1]), fmaxf(a[2], a[3])) + kf_b2[oc];
        sm[OF + tid] = fmaxf(m, 0.f);
    }
    __syncthreads();

    // ---- fc 90->32 + relu ----
    if (tid < 32) {
        float acc = kf_fc1_b[tid];
        const float* wr = &kf_fc1_w[tid * 90];
        for (int i = 0; i < 90; ++i) acc = fmaf(wr[i], sm[OF + i], acc);
        sm[OH + tid] = fmaxf(acc, 0.f);
    }
    __syncthreads();

    // ---- fc 32->40 (dynamic kernels) ----
    if (tid < 40) {
        float acc = kf_fc2_b[tid];
        const float* wr = &kf_fc2_w[tid * 32];
        #pragma unroll
        for (int i = 0; i < 32; ++i) acc = fmaf(wr[i], sm[OH + i], acc);
        sm[OK + tid] = acc;
    }
    __syncthreads();

    // ---- dynamic 2x2 conv (28->27) + pool (->13) + relu : 1690 outputs ----
    for (int idx = tid; idx < 1690; idx += TPB) {
        int oc = idx / 169, rem = idx % 169;
        int py = rem / 13, px = rem % 13;
        float k0 = sm[OK + oc * 4 + 0], k1 = sm[OK + oc * 4 + 1];
        float k2 = sm[OK + oc * 4 + 2], k3 = sm[OK + oc * 4 + 3];
        const float* x0 = &sm[OX + (2 * py) * 28 + 2 * px];
        float v[3][3];
        #pragma unroll
        for (int r = 0; r < 3; ++r)
            #pragma unroll
            for (int c = 0; c < 3; ++c) v[r][c] = x0[r * 28 + c];
        float c00 = v[0][0]*k0 + v[0][1]*k1 + v[1][0]*k2 + v[1][1]*k3;
        float c01 = v[0][1]*k0 + v[0][2]*k1 + v[1][1]*k2 + v[1][2]*k3;
        float c10 = v[1][0]*k0 + v[1][1]*k1 + v[2][0]*k2 + v[2][1]*k3;
        float c11 = v[1][1]*k0 + v[1][2]*k1 + v[2][1]*k2 + v[2][2]*k3;
        float m = fmaxf(fmaxf(c00, c01), fmaxf(c10, c11));
        sm[OY + idx] = fmaxf(m, 0.f);
    }
    __syncthreads();

    // ---- conv2 5x5 [10,13,13]->[20,9,9], split 2-way over ic ----
    if (tid < 360) {
        int h = tid / 180, rem = tid % 180;      // h = ic-half (5 ic each)
        int oc = rem / 9, oy = rem % 9;
        float acc[9];
        #pragma unroll
        for (int i = 0; i < 9; ++i) acc[i] = 0.f;
        for (int icg = 0; icg < 5; ++icg) {
            int ic = 5 * h + icg;
            const float* wb = &sm[OW3 + (oc * 10 + ic) * 25];
            #pragma unroll
            for (int ky = 0; ky < 5; ++ky) {
                const float* yr = &sm[OY + ic * 169 + (oy + ky) * 13];
                float row[13];
                #pragma unroll
                for (int t = 0; t < 13; ++t) row[t] = yr[t];
                #pragma unroll
                for (int kx = 0; kx < 5; ++kx) {
                    float wv = wb[ky * 5 + kx];
                    #pragma unroll
                    for (int ox = 0; ox < 9; ++ox)
                        acc[ox] = fmaf(wv, row[ox + kx], acc[ox]);
                }
            }
        }
        #pragma unroll
        for (int ox = 0; ox < 9; ++ox)
            sm[OW1 + h * 1620 + rem * 9 + ox] = acc[ox];   // partials over dead w1/c1/w2
    }
    __syncthreads();
    // combine halves -> c3 [20,9,9] stored at OY (y is dead now)
    if (tid < 180) {
        int oc = tid / 9;
        float b = conv2_b[oc];
        #pragma unroll
        for (int ox = 0; ox < 9; ++ox)
            sm[OY + tid * 9 + ox] = b + sm[OW1 + tid * 9 + ox] + sm[OW1 + 1620 + tid * 9 + ox];
    }
    __syncthreads();

    // ---- pool (9->4) + relu -> [20,4,4] ----
    if (tid < 320) {
        int oc = tid / 16, rem = tid % 16;
        int py = rem / 4, px = rem % 4;
        const float* c = &sm[OY + oc * 81 + (2 * py) * 9 + 2 * px];
        float m = fmaxf(fmaxf(c[0], c[1]), fmaxf(c[9], c[10]));
        sm[OP3 + tid] = fmaxf(m, 0.f);
    }
    __syncthreads();

    // ---- fc 320->50 + relu, split 8-way over k ----
    if (tid < 400) {
        int g = tid / 50, o = tid % 50;
        const float* wr = &fc1_w[o * 320 + g * 40];
        const float* pp = &sm[OP3 + g * 40];
        float acc = 0.f;
        #pragma unroll
        for (int i = 0; i < 40; ++i) acc = fmaf(wr[i], pp[i], acc);
        sm[OY + tid] = acc;                       // fc partials over dead c3
    }
    __syncthreads();
    if (tid < 50) {
        float acc = fc1_b[tid];
        #pragma unroll
        for (int g = 0; g < 8; ++g) acc += sm[OY + g * 50 + tid];
        sm[OA1 + tid] = fmaxf(acc, 0.f);
    }
    __syncthreads();

    // ---- fc 50->10 ----
    if (tid < 10) {
        float acc = fc2_b[tid];
        const float* wr = &fc2_w[tid * 50];
        #pragma unroll
        for (int i = 0; i < 50; ++i) acc = fmaf(wr[i], sm[OA1 + i], acc);
        sm[OZ + tid] = acc;
    }
    __syncthreads();

    // ---- log_softmax + store ----
    if (tid < 10) {
        float m = sm[OZ + 0];
        #pragma unroll
        for (int i = 1; i < 10; ++i) m = fmaxf(m, sm[OZ + i]);
        float s = 0.f;
        #pragma unroll
        for (int i = 0; i < 10; ++i) s += expf(sm[OZ + i] - m);
        out[n * 10 + tid] = sm[OZ + tid] - m - logf(s);
    }
}

extern "C" void kernel_launch(void* const* d_in, const int* in_sizes, int n_in,
                              void* d_out, int out_size, void* d_ws, size_t ws_size,
                              hipStream_t stream) {
    const float* x        = (const float*)d_in[0];
    const float* kf_w1    = (const float*)d_in[1];
    const float* kf_b1    = (const float*)d_in[2];
    const float* kf_w2    = (const float*)d_in[3];
    const float* kf_b2    = (const float*)d_in[4];
    const float* kf_fc1_w = (const float*)d_in[5];
    const float* kf_fc1_b = (const float*)d_in[6];
    const float* kf_fc2_w = (const float*)d_in[7];
    const float* kf_fc2_b = (const float*)d_in[8];
    const float* conv2_w  = (const float*)d_in[9];
    const float* conv2_b  = (const float*)d_in[10];
    const float* fc1_w    = (const float*)d_in[11];
    const float* fc1_b    = (const float*)d_in[12];
    const float* fc2_w    = (const float*)d_in[13];
    const float* fc2_b    = (const float*)d_in[14];

    const int N = in_sizes[0] / 784;   // 8192

    fused_forward<<<N, TPB, 0, stream>>>(
        x, kf_w1, kf_b1, kf_w2, kf_b2, kf_fc1_w, kf_fc1_b, kf_fc2_w, kf_fc2_b,
        conv2_w, conv2_b, fc1_w, fc1_b, fc2_w, fc2_b, (float*)d_out);
}

// Round 3
// 419.777 us; speedup vs baseline: 1.0222x; 1.0222x over previous
//
#include <hip/hip_runtime.h>
#include <math.h>

#define TPB 256

// ---- LDS layout (float offsets). Weights live in GLOBAL (L2) now. ----
#define OX    0       // 784   x image (alive until dyn conv)
#define OC1   784     // 968   conv7 pooled out [8,11,11]
#define OS    1752    // 3240  scratch: conv5 partials (2880) -> conv2 partials (3240)
#define OY    4992    // 1690  dyn-conv out [10,13,13] -> conv2 raw c3 [20,9,9]
#define OF    6684    // 90
#define OH    6776    // 32
#define OK2   6808    // 40
#define OP3   6848    // 320
#define OPF   7168    // 250   fc320 partials
#define OA1   7420    // 50
#define OZ    7472    // 10
#define SM_TOT 7484   // ~29.9 KB -> 5 blocks/CU

__global__ __launch_bounds__(TPB, 5) void fused_forward(
    const float* __restrict__ x,
    const float* __restrict__ kf_w1, const float* __restrict__ kf_b1,
    const float* __restrict__ kf_w2, const float* __restrict__ kf_b2,
    const float* __restrict__ kf_fc1_w, const float* __restrict__ kf_fc1_b,
    const float* __restrict__ kf_fc2_w, const float* __restrict__ kf_fc2_b,
    const float* __restrict__ conv2_w, const float* __restrict__ conv2_b,
    const float* __restrict__ fc1_w, const float* __restrict__ fc1_b,
    const float* __restrict__ fc2_w, const float* __restrict__ fc2_b,
    float* __restrict__ out)
{
    __shared__ float sm[SM_TOT];
    const int tid = threadIdx.x;
    const int n = blockIdx.x;

    // ---- stage 0: stage x into LDS (float4) ----
    {
        const float4* xg = (const float4*)(x + (long long)n * 784);
        float4* d = (float4*)&sm[OX];
        for (int i = tid; i < 196; i += TPB) d[i] = xg[i];
    }
    __syncthreads();

    // ---- conv7 (28->22) + pool (->11) + relu ----
    // thread = (half, oc, py): 6 pooled outputs in a row (halves overlap at px=5,
    // both compute identical value -> benign same-value double write).
    if (tid < 176) {
        int h = tid / 88, r2 = tid % 88;
        int oc = r2 / 11, py = r2 % 11;
        int cc0 = 10 * h;                    // conv-col / x-col base
        float c[2][12];
        #pragma unroll
        for (int r = 0; r < 2; ++r)
            #pragma unroll
            for (int i = 0; i < 12; ++i) c[r][i] = 0.f;
        float wc[7], wp[7];
        const float* wg = kf_w1 + oc * 49;
        #pragma unroll
        for (int i = 0; i < 7; ++i) wc[i] = wg[i];      // ky = 0
        #pragma unroll
        for (int t = 0; t < 8; ++t) {
            const float* xs = &sm[OX + (2 * py + t) * 28 + cc0];
            float row[18];
            #pragma unroll
            for (int i = 0; i < 18; ++i) row[i] = xs[i];
            if (t <= 6) {                    // conv row 0, ky = t (weights wc)
                #pragma unroll
                for (int kx = 0; kx < 7; ++kx)
                    #pragma unroll
                    for (int cc = 0; cc < 12; ++cc)
                        c[0][cc] = fmaf(wc[kx], row[cc + kx], c[0][cc]);
            }
            if (t >= 1) {                    // conv row 1, ky = t-1 (weights wp)
                #pragma unroll
                for (int kx = 0; kx < 7; ++kx)
                    #pragma unroll
                    for (int cc = 0; cc < 12; ++cc)
                        c[1][cc] = fmaf(wp[kx], row[cc + kx], c[1][cc]);
            }
            #pragma unroll
            for (int i = 0; i < 7; ++i) wp[i] = wc[i];
            if (t < 7) {
                const float* wn = wg + (t + 1) * 7;
                #pragma unroll
                for (int i = 0; i < 7; ++i) wc[i] = wn[i];
            }
        }
        float b = kf_b1[oc];
        #pragma unroll
        for (int j = 0; j < 6; ++j) {
            float m = fmaxf(fmaxf(c[0][2 * j], c[0][2 * j + 1]),
                            fmaxf(c[1][2 * j], c[1][2 * j + 1]));
            sm[OC1 + oc * 121 + py * 11 + 5 * h + j] = fmaxf(m + b, 0.f);
        }
    }
    __syncthreads();

    // ---- conv5: thread = (row-half, oc, ic) computes 3x6 conv partial ----
    if (tid < 160) {
        int hh = tid / 80, rem = tid % 80;
        int oc = rem / 8, ic = rem % 8;
        int r0 = 3 * hh;
        float w[25];
        const float* wg = kf_w2 + (oc * 8 + ic) * 25;
        #pragma unroll
        for (int i = 0; i < 25; ++i) w[i] = wg[i];
        float acc[3][6];
        #pragma unroll
        for (int r = 0; r < 3; ++r)
            #pragma unroll
            for (int i = 0; i < 6; ++i) acc[r][i] = 0.f;
        const float* xb = &sm[OC1 + ic * 121];
        #pragma unroll
        for (int u = 0; u < 7; ++u) {
            const float* xs = xb + (r0 + u) * 11;
            float row[10];
            #pragma unroll
            for (int i = 0; i < 10; ++i) row[i] = xs[i];
            #pragma unroll
            for (int rr = 0; rr < 3; ++rr) {
                int ky = u - rr;
                if (ky >= 0 && ky <= 4) {
                    #pragma unroll
                    for (int kx = 0; kx < 5; ++kx)
                        #pragma unroll
                        for (int cx = 0; cx < 6; ++cx)
                            acc[rr][cx] = fmaf(w[ky * 5 + kx], row[cx + kx], acc[rr][cx]);
                }
            }
        }
        #pragma unroll
        for (int rr = 0; rr < 3; ++rr)
            #pragma unroll
            for (int cx = 0; cx < 6; ++cx)
                sm[OS + ((oc * 8 + ic) * 6 + r0 + rr) * 6 + cx] = acc[rr][cx];
    }
    __syncthreads();
    // reduce over ic + pool + bias + relu -> f[90]
    if (tid < 90) {
        int oc = tid / 9, rem = tid % 9, py = rem / 3, px = rem % 3;
        float s00 = 0.f, s01 = 0.f, s10 = 0.f, s11 = 0.f;
        #pragma unroll
        for (int ic = 0; ic < 8; ++ic) {
            const float* p = &sm[OS + ((oc * 8 + ic) * 6 + 2 * py) * 6 + 2 * px];
            s00 += p[0]; s01 += p[1]; s10 += p[6]; s11 += p[7];
        }
        float m = fmaxf(fmaxf(s00, s01), fmaxf(s10, s11)) + kf_b2[oc];
        sm[OF + tid] = fmaxf(m, 0.f);
    }
    __syncthreads();

    // ---- fc 90->32 + relu ----
    if (tid < 32) {
        float acc = kf_fc1_b[tid];
        const float* wr = &kf_fc1_w[tid * 90];
        for (int i = 0; i < 90; ++i) acc = fmaf(wr[i], sm[OF + i], acc);
        sm[OH + tid] = fmaxf(acc, 0.f);
    }
    __syncthreads();

    // ---- fc 32->40 (dynamic kernels) ----
    if (tid < 40) {
        float acc = kf_fc2_b[tid];
        const float* wr = &kf_fc2_w[tid * 32];
        #pragma unroll
        for (int i = 0; i < 32; ++i) acc = fmaf(wr[i], sm[OH + i], acc);
        sm[OK2 + tid] = acc;
    }
    __syncthreads();

    // ---- dynamic 2x2 conv + pool + relu: thread = (oc, pooled row) ----
    if (tid < 130) {
        int oc = tid / 13, py = tid % 13;
        float k0 = sm[OK2 + oc * 4 + 0], k1 = sm[OK2 + oc * 4 + 1];
        float k2 = sm[OK2 + oc * 4 + 2], k3 = sm[OK2 + oc * 4 + 3];
        const float* x0 = &sm[OX + 2 * py * 28];
        const float* x1 = x0 + 28;
        const float* x2 = x0 + 56;
        float A0 = x0[0], A1 = x1[0], A2 = x2[0];
        float B0 = x0[1], B1 = x1[1], B2 = x2[1];
        #pragma unroll
        for (int j = 0; j < 13; ++j) {
            float C0 = x0[2 * j + 2], C1 = x1[2 * j + 2], C2 = x2[2 * j + 2];
            float c00 = A0 * k0 + B0 * k1 + A1 * k2 + B1 * k3;
            float c01 = B0 * k0 + C0 * k1 + B1 * k2 + C1 * k3;
            float c10 = A1 * k0 + B1 * k1 + A2 * k2 + B2 * k3;
            float c11 = B1 * k0 + C1 * k1 + B2 * k2 + C2 * k3;
            float m = fmaxf(fmaxf(c00, c01), fmaxf(c10, c11));
            sm[OY + oc * 169 + py * 13 + j] = fmaxf(m, 0.f);
            A0 = C0; A1 = C1; A2 = C2;
            if (j < 12) { B0 = x0[2 * j + 3]; B1 = x1[2 * j + 3]; B2 = x2[2 * j + 3]; }
        }
    }
    __syncthreads();

    // ---- conv2 5x5: thread = (ic-half, oc, 3-row group), w in regs ----
    if (tid < 120) {
        int h = tid / 60, rem = tid % 60;
        int oc = rem / 3, rg = rem % 3;
        int r0 = 3 * rg;
        float acc[3][9];
        #pragma unroll
        for (int r = 0; r < 3; ++r)
            #pragma unroll
            for (int i = 0; i < 9; ++i) acc[r][i] = 0.f;
        for (int icg = 0; icg < 5; ++icg) {
            int ic = 5 * h + icg;
            float w[25];
            const float* wg = conv2_w + (oc * 10 + ic) * 25;
            #pragma unroll
            for (int i = 0; i < 25; ++i) w[i] = wg[i];
            const float* yb = &sm[OY + ic * 169];
            #pragma unroll
            for (int u = 0; u < 7; ++u) {
                const float* ys = yb + (r0 + u) * 13;
                float row[13];
                #pragma unroll
                for (int i = 0; i < 13; ++i) row[i] = ys[i];
                #pragma unroll
                for (int rr = 0; rr < 3; ++rr) {
                    int ky = u - rr;
                    if (ky >= 0 && ky <= 4) {
                        #pragma unroll
                        for (int kx = 0; kx < 5; ++kx)
                            #pragma unroll
                            for (int cx = 0; cx < 9; ++cx)
                                acc[rr][cx] = fmaf(w[ky * 5 + kx], row[cx + kx], acc[rr][cx]);
                    }
                }
            }
        }
        #pragma unroll
        for (int rr = 0; rr < 3; ++rr)
            #pragma unroll
            for (int cx = 0; cx < 9; ++cx)
                sm[OS + h * 1620 + ((oc * 3 + rg) * 3 + rr) * 9 + cx] = acc[rr][cx];
    }
    __syncthreads();
    // combine ic-halves + bias -> c3 [20,9,9] at OY (y dead now)
    if (tid < 180) {
        int oc = tid / 9, row = tid % 9;
        int base = ((oc * 3 + row / 3) * 3 + row % 3) * 9;
        float b = conv2_b[oc];
        #pragma unroll
        for (int cx = 0; cx < 9; ++cx)
            sm[OY + oc * 81 + row * 9 + cx] = b + sm[OS + base + cx] + sm[OS + 1620 + base + cx];
    }
    __syncthreads();

    // ---- pool (9->4) + relu -> p3[20,4,4] ----
    for (int idx = tid; idx < 320; idx += TPB) {
        int oc = idx / 16, rem = idx % 16;
        int py = rem / 4, px = rem % 4;
        const float* c = &sm[OY + oc * 81 + (2 * py) * 9 + 2 * px];
        float m = fmaxf(fmaxf(c[0], c[1]), fmaxf(c[9], c[10]));
        sm[OP3 + idx] = fmaxf(m, 0.f);
    }
    __syncthreads();

    // ---- fc 320->50 + relu, 5-way k-split ----
    if (tid < 250) {
        int g = tid / 50, o = tid % 50;
        const float* wr = &fc1_w[o * 320 + g * 64];
        const float* pp = &sm[OP3 + g * 64];
        float acc = 0.f;
        #pragma unroll
        for (int i = 0; i < 64; ++i) acc = fmaf(wr[i], pp[i], acc);
        sm[OPF + tid] = acc;
    }
    __syncthreads();
    if (tid < 50) {
        float acc = fc1_b[tid];
        #pragma unroll
        for (int g = 0; g < 5; ++g) acc += sm[OPF + g * 50 + tid];
        sm[OA1 + tid] = fmaxf(acc, 0.f);
    }
    __syncthreads();

    // ---- fc 50->10 ----
    if (tid < 10) {
        float acc = fc2_b[tid];
        const float* wr = &fc2_w[tid * 50];
        #pragma unroll
        for (int i = 0; i < 50; ++i) acc = fmaf(wr[i], sm[OA1 + i], acc);
        sm[OZ + tid] = acc;
    }
    __syncthreads();

    // ---- log_softmax + store ----
    if (tid < 10) {
        float m = sm[OZ + 0];
        #pragma unroll
        for (int i = 1; i < 10; ++i) m = fmaxf(m, sm[OZ + i]);
        float s = 0.f;
        #pragma unroll
        for (int i = 0; i < 10; ++i) s += expf(sm[OZ + i] - m);
        out[n * 10 + tid] = sm[OZ + tid] - m - logf(s);
    }
}

extern "C" void kernel_launch(void* const* d_in, const int* in_sizes, int n_in,
                              void* d_out, int out_size, void* d_ws, size_t ws_size,
                              hipStream_t stream) {
    const float* x        = (const float*)d_in[0];
    const float* kf_w1    = (const float*)d_in[1];
    const float* kf_b1    = (const float*)d_in[2];
    const float* kf_w2    = (const float*)d_in[3];
    const float* kf_b2    = (const float*)d_in[4];
    const float* kf_fc1_w = (const float*)d_in[5];
    const float* kf_fc1_b = (const float*)d_in[6];
    const float* kf_fc2_w = (const float*)d_in[7];
    const float* kf_fc2_b = (const float*)d_in[8];
    const float* conv2_w  = (const float*)d_in[9];
    const float* conv2_b  = (const float*)d_in[10];
    const float* fc1_w    = (const float*)d_in[11];
    const float* fc1_b    = (const float*)d_in[12];
    const float* fc2_w    = (const float*)d_in[13];
    const float* fc2_b    = (const float*)d_in[14];

    const int N = in_sizes[0] / 784;   // 8192

    fused_forward<<<N, TPB, 0, stream>>>(
        x, kf_w1, kf_b1, kf_w2, kf_b2, kf_fc1_w, kf_fc1_b, kf_fc2_w, kf_fc2_b,
        conv2_w, conv2_b, fc1_w, fc1_b, fc2_w, fc2_b, (float*)d_out);
}

// Round 4
// 319.124 us; speedup vs baseline: 1.3446x; 1.3154x over previous
//
#include <hip/hip_runtime.h>
#include <math.h>

#define TPB 256

// ---- LDS layout (float offsets). Weights live in GLOBAL (L2). ----
#define OX    0       // 784   x image (alive until dyn conv)
#define OC1   784     // 968   conv7 pooled out [8,11,11]
#define OS    1752    // 3240  scratch: conv5 partials (2880) -> conv2 partials (3240)
#define OY    4992    // 1690  dyn-conv out [10,13,13] -> conv2 raw c3 [20,9,9]
#define OF    6684    // 90
#define OH    6776    // 32
#define OK2   6808    // 40
#define OP3   6848    // 320
#define OPF   7168    // 250   fc320 partials
#define OA1   7420    // 50
#define OZ    7472    // 10
#define SM_TOT 7484   // ~29.9 KB

// NOTE: no min-waves arg — R3's (256,5) forced VGPR=48 and spilled the
// register-blocking arrays to scratch (WRITE_SIZE 0.5->237 MB).
__global__ __launch_bounds__(TPB) void fused_forward(
    const float* __restrict__ x,
    const float* __restrict__ kf_w1, const float* __restrict__ kf_b1,
    const float* __restrict__ kf_w2, const float* __restrict__ kf_b2,
    const float* __restrict__ kf_fc1_w, const float* __restrict__ kf_fc1_b,
    const float* __restrict__ kf_fc2_w, const float* __restrict__ kf_fc2_b,
    const float* __restrict__ conv2_w, const float* __restrict__ conv2_b,
    const float* __restrict__ fc1_w, const float* __restrict__ fc1_b,
    const float* __restrict__ fc2_w, const float* __restrict__ fc2_b,
    float* __restrict__ out)
{
    __shared__ float sm[SM_TOT];
    const int tid = threadIdx.x;
    const int n = blockIdx.x;

    // ---- stage 0: stage x into LDS (float4) ----
    {
        const float4* xg = (const float4*)(x + (long long)n * 784);
        float4* d = (float4*)&sm[OX];
        for (int i = tid; i < 196; i += TPB) d[i] = xg[i];
    }
    __syncthreads();

    // ---- conv7 (28->22) + pool (->11) + relu ----
    // thread = (half, oc, py): 6 pooled outputs in a row (halves overlap at px=5,
    // both compute identical value -> benign same-value double write).
    if (tid < 176) {
        int h = tid / 88, r2 = tid % 88;
        int oc = r2 / 11, py = r2 % 11;
        int cc0 = 10 * h;                    // conv-col / x-col base
        float c[2][12];
        #pragma unroll
        for (int r = 0; r < 2; ++r)
            #pragma unroll
            for (int i = 0; i < 12; ++i) c[r][i] = 0.f;
        float wc[7], wp[7];
        const float* wg = kf_w1 + oc * 49;
        #pragma unroll
        for (int i = 0; i < 7; ++i) wc[i] = wg[i];      // ky = 0
        #pragma unroll
        for (int t = 0; t < 8; ++t) {
            const float* xs = &sm[OX + (2 * py + t) * 28 + cc0];
            float row[18];
            #pragma unroll
            for (int i = 0; i < 18; ++i) row[i] = xs[i];
            if (t <= 6) {                    // conv row 0, ky = t (weights wc)
                #pragma unroll
                for (int kx = 0; kx < 7; ++kx)
                    #pragma unroll
                    for (int cc = 0; cc < 12; ++cc)
                        c[0][cc] = fmaf(wc[kx], row[cc + kx], c[0][cc]);
            }
            if (t >= 1) {                    // conv row 1, ky = t-1 (weights wp)
                #pragma unroll
                for (int kx = 0; kx < 7; ++kx)
                    #pragma unroll
                    for (int cc = 0; cc < 12; ++cc)
                        c[1][cc] = fmaf(wp[kx], row[cc + kx], c[1][cc]);
            }
            #pragma unroll
            for (int i = 0; i < 7; ++i) wp[i] = wc[i];
            if (t < 7) {
                const float* wn = wg + (t + 1) * 7;
                #pragma unroll
                for (int i = 0; i < 7; ++i) wc[i] = wn[i];
            }
        }
        float b = kf_b1[oc];
        #pragma unroll
        for (int j = 0; j < 6; ++j) {
            float m = fmaxf(fmaxf(c[0][2 * j], c[0][2 * j + 1]),
                            fmaxf(c[1][2 * j], c[1][2 * j + 1]));
            sm[OC1 + oc * 121 + py * 11 + 5 * h + j] = fmaxf(m + b, 0.f);
        }
    }
    __syncthreads();

    // ---- conv5: thread = (row-half, oc, ic) computes 3x6 conv partial ----
    if (tid < 160) {
        int hh = tid / 80, rem = tid % 80;
        int oc = rem / 8, ic = rem % 8;
        int r0 = 3 * hh;
        float w[25];
        const float* wg = kf_w2 + (oc * 8 + ic) * 25;
        #pragma unroll
        for (int i = 0; i < 25; ++i) w[i] = wg[i];
        float acc[3][6];
        #pragma unroll
        for (int r = 0; r < 3; ++r)
            #pragma unroll
            for (int i = 0; i < 6; ++i) acc[r][i] = 0.f;
        const float* xb = &sm[OC1 + ic * 121];
        #pragma unroll
        for (int u = 0; u < 7; ++u) {
            const float* xs = xb + (r0 + u) * 11;
            float row[10];
            #pragma unroll
            for (int i = 0; i < 10; ++i) row[i] = xs[i];
            #pragma unroll
            for (int rr = 0; rr < 3; ++rr) {
                int ky = u - rr;
                if (ky >= 0 && ky <= 4) {
                    #pragma unroll
                    for (int kx = 0; kx < 5; ++kx)
                        #pragma unroll
                        for (int cx = 0; cx < 6; ++cx)
                            acc[rr][cx] = fmaf(w[ky * 5 + kx], row[cx + kx], acc[rr][cx]);
                }
            }
        }
        #pragma unroll
        for (int rr = 0; rr < 3; ++rr)
            #pragma unroll
            for (int cx = 0; cx < 6; ++cx)
                sm[OS + ((oc * 8 + ic) * 6 + r0 + rr) * 6 + cx] = acc[rr][cx];
    }
    __syncthreads();
    // reduce over ic + pool + bias + relu -> f[90]
    if (tid < 90) {
        int oc = tid / 9, rem = tid % 9, py = rem / 3, px = rem % 3;
        float s00 = 0.f, s01 = 0.f, s10 = 0.f, s11 = 0.f;
        #pragma unroll
        for (int ic = 0; ic < 8; ++ic) {
            const float* p = &sm[OS + ((oc * 8 + ic) * 6 + 2 * py) * 6 + 2 * px];
            s00 += p[0]; s01 += p[1]; s10 += p[6]; s11 += p[7];
        }
        float m = fmaxf(fmaxf(s00, s01), fmaxf(s10, s11)) + kf_b2[oc];
        sm[OF + tid] = fmaxf(m, 0.f);
    }
    __syncthreads();

    // ---- fc 90->32 + relu ----
    if (tid < 32) {
        float acc = kf_fc1_b[tid];
        const float* wr = &kf_fc1_w[tid * 90];
        for (int i = 0; i < 90; ++i) acc = fmaf(wr[i], sm[OF + i], acc);
        sm[OH + tid] = fmaxf(acc, 0.f);
    }
    __syncthreads();

    // ---- fc 32->40 (dynamic kernels) ----
    if (tid < 40) {
        float acc = kf_fc2_b[tid];
        const float* wr = &kf_fc2_w[tid * 32];
        #pragma unroll
        for (int i = 0; i < 32; ++i) acc = fmaf(wr[i], sm[OH + i], acc);
        sm[OK2 + tid] = acc;
    }
    __syncthreads();

    // ---- dynamic 2x2 conv + pool + relu: thread = (oc, pooled row) ----
    if (tid < 130) {
        int oc = tid / 13, py = tid % 13;
        float k0 = sm[OK2 + oc * 4 + 0], k1 = sm[OK2 + oc * 4 + 1];
        float k2 = sm[OK2 + oc * 4 + 2], k3 = sm[OK2 + oc * 4 + 3];
        const float* x0 = &sm[OX + 2 * py * 28];
        const float* x1 = x0 + 28;
        const float* x2 = x0 + 56;
        float A0 = x0[0], A1 = x1[0], A2 = x2[0];
        float B0 = x0[1], B1 = x1[1], B2 = x2[1];
        #pragma unroll
        for (int j = 0; j < 13; ++j) {
            float C0 = x0[2 * j + 2], C1 = x1[2 * j + 2], C2 = x2[2 * j + 2];
            float c00 = A0 * k0 + B0 * k1 + A1 * k2 + B1 * k3;
            float c01 = B0 * k0 + C0 * k1 + B1 * k2 + C1 * k3;
            float c10 = A1 * k0 + B1 * k1 + A2 * k2 + B2 * k3;
            float c11 = B1 * k0 + C1 * k1 + B2 * k2 + C2 * k3;
            float m = fmaxf(fmaxf(c00, c01), fmaxf(c10, c11));
            sm[OY + oc * 169 + py * 13 + j] = fmaxf(m, 0.f);
            A0 = C0; A1 = C1; A2 = C2;
            if (j < 12) { B0 = x0[2 * j + 3]; B1 = x1[2 * j + 3]; B2 = x2[2 * j + 3]; }
        }
    }
    __syncthreads();

    // ---- conv2 5x5: thread = (ic-half, oc, 3-row group), w in regs ----
    if (tid < 120) {
        int h = tid / 60, rem = tid % 60;
        int oc = rem / 3, rg = rem % 3;
        int r0 = 3 * rg;
        float acc[3][9];
        #pragma unroll
        for (int r = 0; r < 3; ++r)
            #pragma unroll
            for (int i = 0; i < 9; ++i) acc[r][i] = 0.f;
        for (int icg = 0; icg < 5; ++icg) {
            int ic = 5 * h + icg;
            float w[25];
            const float* wg = conv2_w + (oc * 10 + ic) * 25;
            #pragma unroll
            for (int i = 0; i < 25; ++i) w[i] = wg[i];
            const float* yb = &sm[OY + ic * 169];
            #pragma unroll
            for (int u = 0; u < 7; ++u) {
                const float* ys = yb + (r0 + u) * 13;
                float row[13];
                #pragma unroll
                for (int i = 0; i < 13; ++i) row[i] = ys[i];
                #pragma unroll
                for (int rr = 0; rr < 3; ++rr) {
                    int ky = u - rr;
                    if (ky >= 0 && ky <= 4) {
                        #pragma unroll
                        for (int kx = 0; kx < 5; ++kx)
                            #pragma unroll
                            for (int cx = 0; cx < 9; ++cx)
                                acc[rr][cx] = fmaf(w[ky * 5 + kx], row[cx + kx], acc[rr][cx]);
                    }
                }
            }
        }
        #pragma unroll
        for (int rr = 0; rr < 3; ++rr)
            #pragma unroll
            for (int cx = 0; cx < 9; ++cx)
                sm[OS + h * 1620 + ((oc * 3 + rg) * 3 + rr) * 9 + cx] = acc[rr][cx];
    }
    __syncthreads();
    // combine ic-halves + bias -> c3 [20,9,9] at OY (y dead now)
    if (tid < 180) {
        int oc = tid / 9, row = tid % 9;
        int base = ((oc * 3 + row / 3) * 3 + row % 3) * 9;
        float b = conv2_b[oc];
        #pragma unroll
        for (int cx = 0; cx < 9; ++cx)
            sm[OY + oc * 81 + row * 9 + cx] = b + sm[OS + base + cx] + sm[OS + 1620 + base + cx];
    }
    __syncthreads();

    // ---- pool (9->4) + relu -> p3[20,4,4] ----
    for (int idx = tid; idx < 320; idx += TPB) {
        int oc = idx / 16, rem = idx % 16;
        int py = rem / 4, px = rem % 4;
        const float* c = &sm[OY + oc * 81 + (2 * py) * 9 + 2 * px];
        float m = fmaxf(fmaxf(c[0], c[1]), fmaxf(c[9], c[10]));
        sm[OP3 + idx] = fmaxf(m, 0.f);
    }
    __syncthreads();

    // ---- fc 320->50 + relu, 5-way k-split ----
    if (tid < 250) {
        int g = tid / 50, o = tid % 50;
        const float* wr = &fc1_w[o * 320 + g * 64];
        const float* pp = &sm[OP3 + g * 64];
        float acc = 0.f;
        #pragma unroll
        for (int i = 0; i < 64; ++i) acc = fmaf(wr[i], pp[i], acc);
        sm[OPF + tid] = acc;
    }
    __syncthreads();
    if (tid < 50) {
        float acc = fc1_b[tid];
        #pragma unroll
        for (int g = 0; g < 5; ++g) acc += sm[OPF + g * 50 + tid];
        sm[OA1 + tid] = fmaxf(acc, 0.f);
    }
    __syncthreads();

    // ---- fc 50->10 ----
    if (tid < 10) {
        float acc = fc2_b[tid];
        const float* wr = &fc2_w[tid * 50];
        #pragma unroll
        for (int i = 0; i < 50; ++i) acc = fmaf(wr[i], sm[OA1 + i], acc);
        sm[OZ + tid] = acc;
    }
    __syncthreads();

    // ---- log_softmax + store ----
    if (tid < 10) {
        float m = sm[OZ + 0];
        #pragma unroll
        for (int i = 1; i < 10; ++i) m = fmaxf(m, sm[OZ + i]);
        float s = 0.f;
        #pragma unroll
        for (int i = 0; i < 10; ++i) s += expf(sm[OZ + i] - m);
        out[n * 10 + tid] = sm[OZ + tid] - m - logf(s);
    }
}

extern "C" void kernel_launch(void* const* d_in, const int* in_sizes, int n_in,
                              void* d_out, int out_size, void* d_ws, size_t ws_size,
                              hipStream_t stream) {
    const float* x        = (const float*)d_in[0];
    const float* kf_w1    = (const float*)d_in[1];
    const float* kf_b1    = (const float*)d_in[2];
    const float* kf_w2    = (const float*)d_in[3];
    const float* kf_b2    = (const float*)d_in[4];
    const float* kf_fc1_w = (const float*)d_in[5];
    const float* kf_fc1_b = (const float*)d_in[6];
    const float* kf_fc2_w = (const float*)d_in[7];
    const float* kf_fc2_b = (const float*)d_in[8];
    const float* conv2_w  = (const float*)d_in[9];
    const float* conv2_b  = (const float*)d_in[10];
    const float* fc1_w    = (const float*)d_in[11];
    const float* fc1_b    = (const float*)d_in[12];
    const float* fc2_w    = (const float*)d_in[13];
    const float* fc2_b    = (const float*)d_in[14];

    const int N = in_sizes[0] / 784;   // 8192

    fused_forward<<<N, TPB, 0, stream>>>(
        x, kf_w1, kf_b1, kf_w2, kf_b2, kf_fc1_w, kf_fc1_b, kf_fc2_w, kf_fc2_b,
        conv2_w, conv2_b, fc1_w, fc1_b, fc2_w, fc2_b, (float*)d_out);
}